// Round 4
// baseline (59672.260 us; speedup 1.0000x reference)
//
#include <hip/hip_runtime.h>
#include <hip/hip_fp16.h>

// TKANCell B=64,T=2048,D=128,U=128,NS=3 — fp32 in/out (R2: WRITE=64MiB).
// 64 independent chains (tf.reshape routes sub-row r=3b'+j to batch b'=r/3).
// R3 post-mortem: compiler picked 64 VGPR + spilled (WRITE +32MB, FETCH +530MB)
// -> same 17.6us/step as R2. R4: __launch_bounds__(512,2) (VGPR cap 256, no
// heuristic spills), wx/wh/dw n-slice cached in LDS as fp16 [k][col] pair-col
// layout (conflict-free b64 reads), gates/aw streamed: fp16 K-contig from ws
// (transposed by convert_w) if ws_size allows, else coalesced fp32 pair-col.

#define TT 2048
#define BB 64

__device__ __forceinline__ float sigf(float x) { return 1.f / (1.f + __expf(-x)); }
__device__ __forceinline__ float tanh_(float x) { return 2.f / (1.f + __expf(-2.f * x)) - 1.f; }

// ---- global fp16 K-contiguous dot, K=128: row of 128 halves vs 64 half2 LDS
__device__ __forceinline__ float dotg128(const __half* __restrict__ Wrow,
                                         const __half* __restrict__ vh) {
    const uint4* W4 = (const uint4*)Wrow;
    const __half2* v2 = (const __half2*)vh;
    float a0 = 0, a1 = 0, a2 = 0, a3 = 0;
#pragma unroll
    for (int bq = 0; bq < 4; ++bq) {
        uint4 w0 = W4[bq * 4 + 0], w1 = W4[bq * 4 + 1];
        uint4 w2 = W4[bq * 4 + 2], w3 = W4[bq * 4 + 3];
        const __half2* h0 = (const __half2*)&w0;
        const __half2* h1 = (const __half2*)&w1;
        const __half2* h2 = (const __half2*)&w2;
        const __half2* h3 = (const __half2*)&w3;
        int k = bq * 16;
#pragma unroll
        for (int m = 0; m < 4; ++m) {
            float2 wa = __half22float2(h0[m]), va = __half22float2(v2[k + m]);
            a0 += wa.x * va.x; a1 += wa.y * va.y;
            float2 wb = __half22float2(h1[m]), vb = __half22float2(v2[k + 4 + m]);
            a2 += wb.x * vb.x; a3 += wb.y * vb.y;
            float2 wc = __half22float2(h2[m]), vc = __half22float2(v2[k + 8 + m]);
            a0 += wc.x * vc.x; a1 += wc.y * vc.y;
            float2 wd = __half22float2(h3[m]), vd = __half22float2(v2[k + 12 + m]);
            a2 += wd.x * vd.x; a3 += wd.y * vd.y;
        }
    }
    return (a0 + a1) + (a2 + a3);
}

// ---- LDS fp16 cached dot, K=128, interleaved layout idx = kk*256 + col*2 + (k&1)
// computes cols 2*ip and 2*ip+1 vs fp32 vector v[128]
__device__ __forceinline__ void dotl128(const __half* __restrict__ mat, int ip,
                                        const float* __restrict__ v,
                                        float& r0, float& r1) {
    float a0 = 0, b0 = 0, a1 = 0, b1 = 0;
#pragma unroll 8
    for (int kk = 0; kk < 64; ++kk) {
        uint2 w = ((const uint2*)(mat + kk * 256))[ip];
        float2 f0 = __half22float2(*(const __half2*)&w.x);  // col 2ip: k=2kk,2kk+1
        float2 f1 = __half22float2(*(const __half2*)&w.y);  // col 2ip+1
        float2 vv = ((const float2*)v)[kk];
        a0 += f0.x * vv.x; b0 += f0.y * vv.y;
        a1 += f1.x * vv.x; b1 += f1.y * vv.y;
    }
    r0 = a0 + b0;
    r1 = a1 + b1;
}

// ---- global fp32 pair-col dot, K=128: cols 2*cp,2*cp+1, row stride `sp` pairs
__device__ __forceinline__ void dotgf(const float* __restrict__ W, int cp, int sp,
                                      const float* __restrict__ v,
                                      float& r0, float& r1) {
    const float2* W2 = (const float2*)W;
    float a0 = 0, a1 = 0, b0 = 0, b1 = 0;
#pragma unroll 8
    for (int k = 0; k < 128; k += 2) {
        float2 w0 = W2[k * sp + cp];
        float2 w1 = W2[(k + 1) * sp + cp];
        a0 += w0.x * v[k];     a1 += w0.y * v[k];
        b0 += w1.x * v[k + 1]; b1 += w1.y * v[k + 1];
    }
    r0 = a0 + b0;
    r1 = a1 + b1;
}

// transpose+fp16: wkT[c][k]@0, wrT[c][k]@49152, awT[u][k]@98304 (halves)
__global__ __launch_bounds__(512) void convert_w(
    const float* __restrict__ Wk, const float* __restrict__ Wr,
    const float* __restrict__ Aw, __half* __restrict__ dst) {
    int g = blockIdx.x * 512 + threadIdx.x;  // 0..147455
    float v;
    if (g < 49152) { int c = g >> 7, k = g & 127; v = Wk[k * 384 + c]; }
    else if (g < 98304) { int gg = g - 49152; int c = gg >> 7, k = gg & 127; v = Wr[k * 384 + c]; }
    else { int gg = g - 98304; int u = gg / 384, k = gg % 384; v = Aw[k * 128 + u]; }
    dst[g] = __float2half(v);
}

template <bool WS>
__global__ __launch_bounds__(512, 2) void tkan(
    const float* __restrict__ xg, const float* __restrict__ Wk,
    const float* __restrict__ Wr, const float* __restrict__ bias,
    const float* __restrict__ Wx, const float* __restrict__ Wh,
    const float* __restrict__ stk, const float* __restrict__ Dw,
    const float* __restrict__ Db, const float* __restrict__ Aw,
    const float* __restrict__ Ab, const __half* __restrict__ wt,
    float* __restrict__ outp) {
    const int bp = blockIdx.x, tid = threadIdx.x;
    const int nmaj = (3 * bp + 1) >> 6;  // n of middle j: covers >=2 of 3 j's

    __shared__ alignas(16) __half wxL[16384];
    __shared__ alignas(16) __half whL[16384];
    __shared__ alignas(16) __half dwL[16384];
    __shared__ alignas(16) __half xhb[128];
    __shared__ alignas(16) __half hhL[128];
    __shared__ alignas(16) __half phL[384];
    __shared__ alignas(16) float xF[4][128];
    __shared__ float hF[128], cS[128], tcS[128];
    __shared__ float sF[384], aF[384], pF[384], g[384];
    __shared__ float part3[640];

    // ---- init: fp16 LDS weight caches from ORIGINAL fp32 layout (k-major)
    for (int idx = tid; idx < 16384; idx += 512) {
        int kk = idx >> 8, r = idx & 255, col = r >> 1, b = r & 1, k = 2 * kk + b;
        int src = nmaj * 16384 + k * 128 + col;
        wxL[idx] = __float2half(Wx[src]);
        whL[idx] = __float2half(Wh[src]);
        dwL[idx] = __float2half(Dw[src]);
    }
    for (int i2 = tid; i2 < 384; i2 += 512) {
        sF[i2] = 0.f; pF[i2] = 0.f; phL[i2] = __float2half(0.f);
    }
    if (tid < 128) { hF[tid] = 0.f; cS[tid] = 0.f; hhL[tid] = __float2half(0.f); }
    if (tid >= 384) {  // x(t=0)
        int l = tid - 384, v_ = l >> 5, fe = l & 31;
        int bsrc = (v_ == 0) ? bp : ((3 * bp + (v_ - 1)) & 63);
        float4 w = ((const float4*)(xg + (size_t)bsrc * TT * 128))[fe];
        xF[v_][fe * 4 + 0] = w.x; xF[v_][fe * 4 + 1] = w.y;
        xF[v_][fe * 4 + 2] = w.z; xF[v_][fe * 4 + 3] = w.w;
        if (v_ == 0) {
            ((__half2*)xhb)[fe * 2] = __floats2half2_rn(w.x, w.y);
            ((__half2*)xhb)[fe * 2 + 1] = __floats2half2_rn(w.z, w.w);
        }
    }
    __syncthreads();

    for (int t = 0; t < TT; ++t) {
        // ================= Phase 1: gates g[384] + agg aF[384] =================
        if (WS) {
            if (tid < 320) {
                for (int c = tid; c < 384; c += 320) {
                    float acc = dotg128(wt + c * 128, xhb)
                              + dotg128(wt + 49152 + c * 128, hhL) + bias[c];
                    g[c] = acc;
                }
            } else {
                int ag = tid - 320;  // 0..191: (j, ipair)
                int j = ag >> 6, ip = ag & 63;
                int nj = (3 * bp + j) >> 6;
                float r0, r1, q0, q1;
                if (nj == nmaj) {
                    dotl128(wxL, ip, xF[1 + j], r0, r1);
                    dotl128(whL, ip, sF + j * 128, q0, q1);
                } else {
                    dotgf(Wx + nj * 16384, ip, 64, xF[1 + j], r0, r1);
                    dotgf(Wh + nj * 16384, ip, 64, sF + j * 128, q0, q1);
                }
                aF[j * 128 + 2 * ip] = r0 + q0;
                aF[j * 128 + 2 * ip + 1] = r1 + q1;
            }
        } else {
            if (tid < 192) {
                float r0, r1, q0, q1;
                dotgf(Wk, tid, 192, xF[0], r0, r1);
                dotgf(Wr, tid, 192, hF, q0, q1);
                g[2 * tid] = r0 + q0 + bias[2 * tid];
                g[2 * tid + 1] = r1 + q1 + bias[2 * tid + 1];
            } else if (tid >= 320) {
                int ag = tid - 320;
                int j = ag >> 6, ip = ag & 63;
                int nj = (3 * bp + j) >> 6;
                float r0, r1, q0, q1;
                if (nj == nmaj) {
                    dotl128(wxL, ip, xF[1 + j], r0, r1);
                    dotl128(whL, ip, sF + j * 128, q0, q1);
                } else {
                    dotgf(Wx + nj * 16384, ip, 64, xF[1 + j], r0, r1);
                    dotgf(Wh + nj * 16384, ip, 64, sF + j * 128, q0, q1);
                }
                aF[j * 128 + 2 * ip] = r0 + q0;
                aF[j * 128 + 2 * ip + 1] = r1 + q1;
            }
        }
        __syncthreads();

        // ================= Phase 2: p = relu(a@Dw+Db) ; c-update ===============
        if (tid < 192) {
            int j = tid >> 6, op = tid & 63;
            int nj = (3 * bp + j) >> 6;
            float r0, r1;
            if (nj == nmaj) dotl128(dwL, op, aF + j * 128, r0, r1);
            else            dotgf(Dw + nj * 16384, op, 64, aF + j * 128, r0, r1);
            float2 db = ((const float2*)(Db + nj * 128))[op];
            r0 = fmaxf(r0 + db.x, 0.f);
            r1 = fmaxf(r1 + db.y, 0.f);
            int q = j * 128 + 2 * op;
            pF[q] = r0; pF[q + 1] = r1;
            phL[q] = __float2half(r0); phL[q + 1] = __float2half(r1);
        } else if (tid >= 384) {
            int u = tid - 384;
            float gi = sigf(g[u]);
            float gf = sigf(g[128 + u]);
            float gc = sigf(g[256 + u]);
            float cn = gf * cS[u] + gi * tanh_(gc);
            cS[u] = cn;
            tcS[u] = tanh_(cn);
        }
        __syncthreads();

        // ================= Phase 3: y-partials = p @ Aw ; x-prefetch ===========
        if (WS) {
            if (tid < 384) {
                int u = tid & 127, kc = tid >> 7;
                part3[u * 5 + kc] = dotg128(wt + 98304 + u * 384 + kc * 128,
                                            phL + kc * 128);
            }
        } else {
            if (tid < 192) {
                int up = tid & 63, kc = tid >> 6;
                float r0, r1;
                dotgf(Aw + kc * 128 * 128, up, 64, pF + kc * 128, r0, r1);
                part3[(2 * up) * 5 + kc] = r0;
                part3[(2 * up + 1) * 5 + kc] = r1;
            }
        }
        if (tid >= 384) {  // prefetch x(t+1) into xF/xhb (P1 readers are done)
            int l = tid - 384, v_ = l >> 5, fe = l & 31;
            int tn = (t + 1 < TT) ? t + 1 : TT - 1;
            int bsrc = (v_ == 0) ? bp : ((3 * bp + (v_ - 1)) & 63);
            float4 w = ((const float4*)(xg + ((size_t)bsrc * TT + tn) * 128))[fe];
            xF[v_][fe * 4 + 0] = w.x; xF[v_][fe * 4 + 1] = w.y;
            xF[v_][fe * 4 + 2] = w.z; xF[v_][fe * 4 + 3] = w.w;
            if (v_ == 0) {
                ((__half2*)xhb)[fe * 2] = __floats2half2_rn(w.x, w.y);
                ((__half2*)xhb)[fe * 2 + 1] = __floats2half2_rn(w.z, w.w);
            }
        }
        __syncthreads();

        // ================= Phase 4: finalize h, out ; s-update ================
        if (tid < 128) {
            float y = part3[tid * 5] + part3[tid * 5 + 1] + part3[tid * 5 + 2]
                    + Ab[tid];
            float hn = sigf(y) * tcS[tid];
            hF[tid] = hn;
            hhL[tid] = __float2half(hn);
            outp[((size_t)bp * TT + t) * 128 + tid] = hn;
        } else {
            int q = tid - 128;  // 0..383
            int j = q >> 7, o = q & 127;
            int nj = (3 * bp + j) >> 6;
            float sn = stk[nj * 256 + o] * __half2float(phL[q])
                     + stk[nj * 256 + 128 + o] * sF[q];
            sF[q] = sn;
        }
        __syncthreads();
    }
}

extern "C" void kernel_launch(void* const* d_in, const int* in_sizes, int n_in,
                              void* d_out, int out_size, void* d_ws, size_t ws_size,
                              hipStream_t stream) {
    const float* x    = (const float*)d_in[0];
    const float* Wk   = (const float*)d_in[1];
    const float* Wr   = (const float*)d_in[2];
    const float* bias = (const float*)d_in[3];
    const float* Wx   = (const float*)d_in[4];
    const float* Wh   = (const float*)d_in[5];
    const float* stk  = (const float*)d_in[6];
    const float* Dw   = (const float*)d_in[7];
    const float* Db   = (const float*)d_in[8];
    const float* Aw   = (const float*)d_in[9];
    const float* Ab   = (const float*)d_in[10];
    float* outp = (float*)d_out;

    const size_t needW = 147456 * sizeof(__half);  // 294,912 B
    if (ws_size >= needW) {
        __half* wt = (__half*)d_ws;
        convert_w<<<dim3(288), dim3(512), 0, stream>>>(Wk, Wr, Aw, wt);
        tkan<true><<<dim3(BB), dim3(512), 0, stream>>>(
            x, Wk, Wr, bias, Wx, Wh, stk, Dw, Db, Aw, Ab, wt, outp);
    } else {
        tkan<false><<<dim3(BB), dim3(512), 0, stream>>>(
            x, Wk, Wr, bias, Wx, Wh, stk, Dw, Db, Aw, Ab, (const __half*)nullptr,
            outp);
    }
}

// Round 5
// 21792.421 us; speedup vs baseline: 2.7382x; 2.7382x over previous
//
#include <hip/hip_runtime.h>
#include <hip/hip_fp16.h>

// TKANCell B=64,T=2048,D=128,U=128,NS=3 — fp32 in/out (R2: WRITE=64MiB).
// 64 independent chains (tf.reshape routes sub-row r=3b'+j to batch b'=r/3).
// R3/R4 post-mortem: compiler's occupancy heuristic picks low VGPR and spills
// complex phases (R4 WRITE=4.6GB). R5: simple quad-col dots (1 float4 acc,
// unroll 8, ~50 live VGPR), launch_bounds(512,1); x-projections (Wk,Wx)
// amortized over 32-step chunks into LDS fp16; serial loop streams only
// Wr/Wh/Dw/Aw (fp16 from ws if ws_size>=393KB, else fp32 originals).
// NOWS instance carries +16KB dummy LDS so LDS_Block_Size reveals which ran.

#define TT 2048
#define BB 64
#define TC 32

typedef unsigned int u32;

__device__ __forceinline__ float sigf(float x) { return 1.f / (1.f + __expf(-x)); }
__device__ __forceinline__ float tanh_(float x) { return 2.f / (1.f + __expf(-2.f * x)) - 1.f; }
__device__ __forceinline__ float2 h2f2(u32 u) {
    __half2 h = *(__half2*)&u;
    return __half22float2(h);
}

// acc += W[k][quad*4 .. +3] * v[k] over k in [k0,k0+kn).
// idxBase/stride in quad units (uint2 for fp16, float4 for fp32 — same index).
template <bool WS>
__device__ __forceinline__ void dotq(const void* W, int idxBase, int stride,
                                     const float* __restrict__ v, int k0, int kn,
                                     float4& acc) {
    if (WS) {
        const uint2* Wp = (const uint2*)W;
#pragma unroll 8
        for (int k = k0; k < k0 + kn; ++k) {
            uint2 w = Wp[idxBase + k * stride];
            float2 lo = h2f2(w.x), hi = h2f2(w.y);
            float xv = v[k];
            acc.x += lo.x * xv; acc.y += lo.y * xv;
            acc.z += hi.x * xv; acc.w += hi.y * xv;
        }
    } else {
        const float4* Wp = (const float4*)W;
#pragma unroll 8
        for (int k = k0; k < k0 + kn; ++k) {
            float4 w = Wp[idxBase + k * stride];
            float xv = v[k];
            acc.x += w.x * xv; acc.y += w.y * xv;
            acc.z += w.z * xv; acc.w += w.w * xv;
        }
    }
}

// fp16 copy of Wr|Wh|Dw|Aw (each 49152 elems, layout preserved).
__global__ __launch_bounds__(512) void convert_w(
    const float* __restrict__ Wr, const float* __restrict__ Wh,
    const float* __restrict__ Dw, const float* __restrict__ Aw,
    __half* __restrict__ dst) {
    int g = blockIdx.x * 512 + threadIdx.x;  // 0..196607
    int seg = g / 49152, idx = g % 49152;
    const float* src = (seg == 0) ? Wr : (seg == 1) ? Wh : (seg == 2) ? Dw : Aw;
    dst[g] = __float2half(src[idx]);
}

template <bool WS>
__global__ __launch_bounds__(512, 1) void tkan(
    const float* __restrict__ xg, const float* __restrict__ Wk,
    const float* __restrict__ Wr, const float* __restrict__ bias,
    const float* __restrict__ Wx, const float* __restrict__ Wh,
    const float* __restrict__ stk, const float* __restrict__ Dw,
    const float* __restrict__ Db, const float* __restrict__ Aw,
    const float* __restrict__ Ab, const __half* __restrict__ wt,
    float* __restrict__ outp) {
    const int bp = blockIdx.x, tid = threadIdx.x;

    __shared__ float xC[4][TC][128];          // 64KB chunk x rows
    __shared__ __half gxL[TC][384];           // 24KB x@Wk per chunk
    __shared__ __half axL[TC][384];           // 24KB x@Wx per chunk
    __shared__ float hS[128], cS[128], tcS[128];
    __shared__ float sS[384], aS[384], pS[384], gS[384];
    __shared__ float part1[384][4], part2[192][4], part3[256][4];
    __shared__ float biasL[384], stkj[3][2][128], DbL[3][128], AbL[128];
    __shared__ float dummy[WS ? 4 : 4096];    // LDS_Block_Size marker

    // ---- init
    if (tid < 128) { hS[tid] = 0.f; cS[tid] = 0.f; AbL[tid] = Ab[tid]; }
    if (tid >= 128 && tid < 512) {
        int q = tid - 128;
        sS[q] = 0.f;
        biasL[q] = bias[q];
    }
    {
        // per-j constants: nj = (3bp+j)>>6
        int j = tid >> 7, o = tid & 127;
        if (j < 3) {
            int nj = (3 * bp + j) >> 6;
            stkj[j][0][o] = stk[nj * 256 + o];
            stkj[j][1][o] = stk[nj * 256 + 128 + o];
            DbL[j][o] = Db[nj * 128 + o];
        }
    }
    if (bias[0] > 1e30f) { dummy[tid & 3] = 1.f; }  // never true; keeps dummy alive
    __syncthreads();

    const float4* Wk4 = (const float4*)Wk;   // row stride 96 quads
    const float4* Wx4 = (const float4*)Wx;   // slice 4096 quads, stride 32
    const void* wWr = WS ? (const void*)(wt)          : (const void*)Wr;
    const void* wWh = WS ? (const void*)(wt + 49152)  : (const void*)Wh;
    const void* wDw = WS ? (const void*)(wt + 98304)  : (const void*)Dw;
    const void* wAw = WS ? (const void*)(wt + 147456) : (const void*)Aw;

    for (int t = 0; t < TT; ++t) {
        int tt = t & (TC - 1);
        if (tt == 0) {
            // ===== chunk phase: stage x rows, compute gx/ax for TC steps =====
            // stage: 4096 float4 loads
            for (int f = tid; f < 4096; f += 512) {
                int v_ = f >> 10, ti = (f >> 5) & 31, kq = f & 31;
                int row = (v_ == 0) ? bp : ((3 * bp + (v_ - 1)) & 63);
                float4 w = ((const float4*)(xg + ((size_t)row * TT + t + ti) * 128))[kq];
                float* d = &xC[v_][ti][kq * 4];
                d[0] = w.x; d[1] = w.y; d[2] = w.z; d[3] = w.w;
            }
            __syncthreads();
            // compute: TC*192 quad tasks
            for (int ct = tid; ct < TC * 192; ct += 512) {
                int ti = ct / 192, r = ct % 192;
                float4 acc = {0.f, 0.f, 0.f, 0.f};
                int qout;
                if (r < 96) {  // gx quad r
                    const float* v = xC[0][ti];
#pragma unroll 8
                    for (int k = 0; k < 128; ++k) {
                        float4 w = Wk4[k * 96 + r];
                        float xv = v[k];
                        acc.x += w.x * xv; acc.y += w.y * xv;
                        acc.z += w.z * xv; acc.w += w.w * xv;
                    }
                    qout = r;
                    ((__half2*)&gxL[ti][0])[2 * qout] = __floats2half2_rn(acc.x, acc.y);
                    ((__half2*)&gxL[ti][0])[2 * qout + 1] = __floats2half2_rn(acc.z, acc.w);
                } else {       // ax: j = (r-96)/32, quad qi = (r-96)%32
                    int jq = r - 96, j = jq >> 5, qi = jq & 31;
                    int nj = (3 * bp + j) >> 6;
                    const float* v = xC[1 + j][ti];
#pragma unroll 8
                    for (int k = 0; k < 128; ++k) {
                        float4 w = Wx4[nj * 4096 + k * 32 + qi];
                        float xv = v[k];
                        acc.x += w.x * xv; acc.y += w.y * xv;
                        acc.z += w.z * xv; acc.w += w.w * xv;
                    }
                    qout = 32 * j + qi + 96 - 96;  // col base = j*128 + qi*4
                    int cq = j * 32 + qi;
                    ((__half2*)&axL[ti][0])[2 * cq] = __floats2half2_rn(acc.x, acc.y);
                    ((__half2*)&axL[ti][0])[2 * cq + 1] = __floats2half2_rn(acc.z, acc.w);
                }
            }
            __syncthreads();
        }

        // ===== S1: Wr (h->gates) + Wh (s->agg) partials; K split in 2 =====
        if (tid < 384) {
            float4 acc = {0.f, 0.f, 0.f, 0.f};
            if (tid < 192) {          // Wr: quad q, ks
                int q = tid % 96, ks = tid / 96;
                dotq<WS>(wWr, q, 96, hS, ks * 64, 64, acc);
            } else {                  // Wh: jq (j,qi), ks
                int t2 = tid - 192;
                int jq = t2 % 96, ks = t2 / 96;
                int j = jq >> 5, qi = jq & 31;
                int nj = (3 * bp + j) >> 6;
                dotq<WS>(wWh, nj * 4096 + qi, 32, sS + j * 128, ks * 64, 64, acc);
            }
            *(float4*)&part1[tid][0] = acc;
        }
        __syncthreads();

        // ===== S1r: reduce + add gx/ax(+bias) -> gS, aS =====
        if (tid < 192) {
            if (tid < 96) {
                int q = tid;
                float4 a0 = *(float4*)&part1[q][0];
                float4 a1 = *(float4*)&part1[q + 96][0];
                float2 g0 = h2f2(((const u32*)&gxL[tt][0])[2 * q]);
                float2 g1 = h2f2(((const u32*)&gxL[tt][0])[2 * q + 1]);
                float4 r;
                r.x = a0.x + a1.x + g0.x + biasL[4 * q];
                r.y = a0.y + a1.y + g0.y + biasL[4 * q + 1];
                r.z = a0.z + a1.z + g1.x + biasL[4 * q + 2];
                r.w = a0.w + a1.w + g1.y + biasL[4 * q + 3];
                *(float4*)&gS[4 * q] = r;
            } else {
                int cq = tid - 96;  // 0..95 over a-cols
                float4 a0 = *(float4*)&part1[192 + cq][0];
                float4 a1 = *(float4*)&part1[288 + cq][0];
                float2 g0 = h2f2(((const u32*)&axL[tt][0])[2 * cq]);
                float2 g1 = h2f2(((const u32*)&axL[tt][0])[2 * cq + 1]);
                float4 r;
                r.x = a0.x + a1.x + g0.x;
                r.y = a0.y + a1.y + g0.y;
                r.z = a0.z + a1.z + g1.x;
                r.w = a0.w + a1.w + g1.y;
                *(float4*)&aS[4 * cq] = r;
            }
        }
        __syncthreads();

        // ===== S2: Dw partials (K split 2) ; c-update on threads 384+ =====
        if (tid < 192) {
            int q = tid % 96, ks = tid / 96;
            int j = q >> 5, qi = q & 31;
            int nj = (3 * bp + j) >> 6;
            float4 acc = {0.f, 0.f, 0.f, 0.f};
            dotq<WS>(wDw, nj * 4096 + qi, 32, aS + j * 128, ks * 64, 64, acc);
            *(float4*)&part2[tid][0] = acc;
        } else if (tid >= 384) {
            int u = tid - 384;
            float gi = sigf(gS[u]);
            float gf = sigf(gS[128 + u]);
            float gc = sigf(gS[256 + u]);
            float cn = gf * cS[u] + gi * tanh_(gc);
            cS[u] = cn;
            tcS[u] = tanh_(cn);
        }
        __syncthreads();

        // ===== S2r: p = relu(. + Db) =====
        if (tid < 96) {
            int j = tid >> 5, o = (tid & 31) * 4;  // col in [0,128)
            float4 a0 = *(float4*)&part2[tid][0];
            float4 a1 = *(float4*)&part2[tid + 96][0];
            float4 r;
            r.x = fmaxf(a0.x + a1.x + DbL[j][o], 0.f);
            r.y = fmaxf(a0.y + a1.y + DbL[j][o + 1], 0.f);
            r.z = fmaxf(a0.z + a1.z + DbL[j][o + 2], 0.f);
            r.w = fmaxf(a0.w + a1.w + DbL[j][o + 3], 0.f);
            *(float4*)&pS[4 * tid] = r;
        }
        __syncthreads();

        // ===== S3: Aw partials (32 quads x K-split 8) ; s-update =====
        if (tid < 256) {
            int q = tid & 31, ks = tid >> 5;  // K=48 each
            float4 acc = {0.f, 0.f, 0.f, 0.f};
            dotq<WS>(wAw, q, 32, pS, ks * 48, 48, acc);
            *(float4*)&part3[tid][0] = acc;
        } else if (tid < 384) {
            int e = tid - 256;
#pragma unroll
            for (int j = 0; j < 3; ++j) {
                int q = j * 128 + e;
                sS[q] = stkj[j][0][e] * pS[q] + stkj[j][1][e] * sS[q];
            }
        }
        __syncthreads();

        // ===== S3r: finalize h, write out =====
        if (tid < 128) {
            int u = tid;
            float y = AbL[u];
#pragma unroll
            for (int ks = 0; ks < 8; ++ks) y += part3[ks * 32 + (u >> 2)][u & 3];
            float hn = sigf(y) * tcS[u];
            hS[u] = hn;
            outp[((size_t)bp * TT + t) * 128 + u] = hn;
        }
        __syncthreads();
    }
}

extern "C" void kernel_launch(void* const* d_in, const int* in_sizes, int n_in,
                              void* d_out, int out_size, void* d_ws, size_t ws_size,
                              hipStream_t stream) {
    const float* x    = (const float*)d_in[0];
    const float* Wk   = (const float*)d_in[1];
    const float* Wr   = (const float*)d_in[2];
    const float* bias = (const float*)d_in[3];
    const float* Wx   = (const float*)d_in[4];
    const float* Wh   = (const float*)d_in[5];
    const float* stk  = (const float*)d_in[6];
    const float* Dw   = (const float*)d_in[7];
    const float* Db   = (const float*)d_in[8];
    const float* Aw   = (const float*)d_in[9];
    const float* Ab   = (const float*)d_in[10];
    float* outp = (float*)d_out;

    const size_t needW = 196608 * sizeof(__half);  // 393,216 B
    if (ws_size >= needW) {
        __half* wt = (__half*)d_ws;
        convert_w<<<dim3(384), dim3(512), 0, stream>>>(Wr, Wh, Dw, Aw, wt);
        tkan<true><<<dim3(BB), dim3(512), 0, stream>>>(
            x, Wk, Wr, bias, Wx, Wh, stk, Dw, Db, Aw, Ab, wt, outp);
    } else {
        tkan<false><<<dim3(BB), dim3(512), 0, stream>>>(
            x, Wk, Wr, bias, Wx, Wh, stk, Dw, Db, Aw, Ab, (const __half*)nullptr,
            outp);
    }
}